// Round 2
// baseline (76.607 us; speedup 1.0000x reference)
//
#include <hip/hip_runtime.h>

// Problem constants (match reference)
#define BB   16384
#define SS   20
#define DD   128
#define NBB  2          // batch rows per 256-thread block
#define ROWW (DD + 8)   // +4 zero pad each side for dilation-4 taps
#define EPSV 1e-5f

__global__ __launch_bounds__(256) void fused_mdt_kernel(
    const int*   __restrict__ tokens,   // [B,S]
    const float* __restrict__ emb,      // [V,D] (6 KB, L1/L2-resident)
    const float* __restrict__ pre_w,    // [S]
    const float* __restrict__ w0, const float* __restrict__ b0,  // [S,1,3],[S]
    const float* __restrict__ w1, const float* __restrict__ b1,
    const float* __restrict__ w2, const float* __restrict__ b2,
    const float* __restrict__ gate_w,   // [S,S] (t,s)
    const float* __restrict__ gate_b,   // [S]
    const float* __restrict__ post_w,   // [S]
    const float* __restrict__ logit_w,  // [1,S,1] -> flat [S]
    float*       __restrict__ out)      // [B,1,D] -> flat [B*D]
{
    __shared__ float s_xn[NBB][SS][ROWW];   // 21.76 KB -> 7 blocks/CU

    const int tid = threadIdx.x;
    const int bl  = tid >> 7;          // wave-uniform: waves 0,1 -> bl=0; waves 2,3 -> bl=1
    const int d   = tid & 127;
    // b is wave-uniform; readfirstlane lets tokens become scalar loads
    const int b   = __builtin_amdgcn_readfirstlane(blockIdx.x * NBB + bl);

    // zero the conv pads (one-time, before the single barrier)
    for (int p = tid; p < NBB * SS * 8; p += 256) {
        int bb  = p / (SS * 8);
        int rem = p - bb * (SS * 8);
        int s = rem >> 3, k = rem & 7;
        int j = (k < 4) ? k : (DD + k);    // 0..3 | 132..135
        s_xn[bb][s][j] = 0.f;
    }

    const int* tb = tokens + b * SS;       // uniform base -> s_load

    // ---- phase 1: x = emb[tok], ms over S, residual dot acc1 ----
    float xv[SS];
    float ms = 0.f, acc1 = 0.f;
    #pragma unroll
    for (int s = 0; s < SS; ++s) {
        int   t = tb[s];                   // scalar load (wave-uniform)
        float x = emb[t * DD + d];         // coalesced 256B/wave, cache-resident
        xv[s] = x;
        ms   = fmaf(x, x, ms);
        acc1 = fmaf(x, logit_w[s], acc1);
    }
    const float r = rsqrtf(ms * (1.f / SS) + EPSV);

    #pragma unroll
    for (int s = 0; s < SS; ++s)
        s_xn[bl][s][4 + d] = xv[s] * (r * pre_w[s]);   // xv dies here

    __syncthreads();   // the only barrier

    // ---- phase 2+3 merged, s-outer: conv taps + gate accumulation ----
    float g[SS], xd[SS];
    #pragma unroll
    for (int t = 0; t < SS; ++t) g[t] = gate_b[t];

    #pragma unroll
    for (int s = 0; s < SS; ++s) {
        const float* row = &s_xn[bl][s][4 + d];
        const float  c   = row[0];
        // conv: 6 neighbor taps + merged center tap, bias folded into init
        float acc = b0[s] + b1[s] + b2[s];
        acc = fmaf(w0[s*3+0], row[-1], acc);
        acc = fmaf(w0[s*3+2], row[ 1], acc);
        acc = fmaf(w1[s*3+0], row[-2], acc);
        acc = fmaf(w1[s*3+2], row[ 2], acc);
        acc = fmaf(w2[s*3+0], row[-4], acc);
        acc = fmaf(w2[s*3+2], row[ 4], acc);
        acc = fmaf(w0[s*3+1] + w1[s*3+1] + w2[s*3+1], c, acc);
        xd[s] = acc;
        // gate: column s of gate_w into 20 accumulators (SGPR operands)
        #pragma unroll
        for (int t = 0; t < SS; ++t)
            g[t] = fmaf(c, gate_w[t * SS + s], g[t]);
    }

    // ---- final: SiLU, post-RMSNorm stats, output ----
    float ms2 = 0.f, acc2 = 0.f;
    #pragma unroll
    for (int t = 0; t < SS; ++t) {
        float gv = g[t];
        float sg = __builtin_amdgcn_rcpf(1.f + __expf(-gv));
        float h  = xd[t] * (gv * sg);
        ms2  = fmaf(h, h, ms2);
        acc2 = fmaf(h, post_w[t] * logit_w[t], acc2);
    }
    const float r2 = rsqrtf(ms2 * (1.f / SS) + EPSV);

    out[b * DD + d] = acc1 + r2 * acc2;
}

extern "C" void kernel_launch(void* const* d_in, const int* in_sizes, int n_in,
                              void* d_out, int out_size, void* d_ws, size_t ws_size,
                              hipStream_t stream) {
    const int*   tokens  = (const int*)  d_in[0];
    // d_in[1] = number_log — unused by the reference
    const float* emb     = (const float*)d_in[2];
    const float* pre_w   = (const float*)d_in[3];
    const float* w0      = (const float*)d_in[4];
    const float* b0      = (const float*)d_in[5];
    const float* w1      = (const float*)d_in[6];
    const float* b1      = (const float*)d_in[7];
    const float* w2      = (const float*)d_in[8];
    const float* b2      = (const float*)d_in[9];
    const float* gate_w  = (const float*)d_in[10];
    const float* gate_b  = (const float*)d_in[11];
    const float* post_w  = (const float*)d_in[12];
    const float* logit_w = (const float*)d_in[13];
    float*       out     = (float*)d_out;

    dim3 grid(BB / NBB);   // 8192 blocks
    dim3 block(256);
    hipLaunchKernelGGL(fused_mdt_kernel, grid, block, 0, stream,
                       tokens, emb, pre_w, w0, b0, w1, b1, w2, b2,
                       gate_w, gate_b, post_w, logit_w, out);
}